// Round 14
// baseline (5871.632 us; speedup 1.0000x reference)
//
#include <hip/hip_runtime.h>
#include <hip/hip_bf16.h>
#include <cstdint>

// ---------------------------------------------------------------------------
// BiLSTM layer, persistent kernel (round 14 = r5 base, x in REGISTERS).
//   B=64, S=512, I=H=1024.  out = [fwd(B,S,H) | bwd(B,S,H)] fp32.
// 256 blocks x 512 threads (8 waves), 1 block/CU. dir=bid&1, db=bid>>1.
// Weights (W_ih|W_hh, K=2048) VGPR-resident as MFMA B-fragments.
// h exchange: agent write-through stores -> MALL; SC0|SC1 bypass DMA loads
// into PA/PB with the r2-r5-proven l^i swizzle (conflict data known).
//
// ROUND-14: the per-CU staged-byte budget (256KB fp32 x through a full LDS
// round trip + block drains, every round since r2) is the last invariant.
// Each wave's x A-fragments are only 64 VGPR/thread -> load x DIRECTLY INTO
// REGISTERS in the post-release shadow (fp32+cvt, or bf16 direct if the ws
// fits the precomputed buffer), compute from regs at step top:
//   - x-LDS traffic eliminated (576->320 KB/step/CU), B1 barrier+drain gone.
//   - load latency lives in the shadow, covered by the poll window.
//   - PA/PB are h-only; H phase, poll, partials, gates = r5 verbatim.
// r12/r13 lesson encoded: no new swizzles anywhere; x frag reads are
// 16B/32B at native offsets (full sector coverage per row across the wave).
// ---------------------------------------------------------------------------

typedef __bf16 bf16_t;
typedef bf16_t bf16x8 __attribute__((ext_vector_type(8)));
typedef float  f32x4  __attribute__((ext_vector_type(4)));

#define DEVI __device__ __forceinline__

constexpr int Bb = 64, Ss = 512, Ii = 1024, Hh = 1024;
constexpr size_t WS_FLAGS  = 0;            // 256 ints (2 dirs x 128 blocks)
constexpr size_t WS_HRING  = 4096;         // 2*2*64*1024 bf16 = 524288 B
constexpr size_t WS_XBF    = 528384;       // x bf16 t-major (compact layout)
constexpr size_t XBF_BYTES = 2ull * Ss * Bb * Ii * 2;   // 128 MiB
constexpr size_t WS_NEED_XBF = WS_XBF + XBF_BYTES;      // ~128.5 MiB
constexpr int LDS_TOTAL = 163840;          // PA 64K | PB 64K | part 32K

DEVI float fast_sig(float x) {
  float z = __expf(-fabsf(x));
  float r = __builtin_amdgcn_rcpf(1.f + z);
  return x >= 0.f ? r : z * r;
}
DEVI float fast_tanh(float x) {
  float z = __expf(-2.f * fabsf(x));
  float r = (1.f - z) * __builtin_amdgcn_rcpf(1.f + z);
  return x >= 0.f ? r : -r;
}
DEVI bf16x8 cvt8(f32x4 a, f32x4 b) {
  bf16x8 r;
  r[0] = (bf16_t)a[0]; r[1] = (bf16_t)a[1]; r[2] = (bf16_t)a[2]; r[3] = (bf16_t)a[3];
  r[4] = (bf16_t)b[0]; r[5] = (bf16_t)b[1]; r[6] = (bf16_t)b[2]; r[7] = (bf16_t)b[3];
  return r;
}
DEVI uint32_t pk_bf16(float lo, float hi) {
  union { bf16_t b[2]; uint32_t u; } x;
  x.b[0] = (bf16_t)lo; x.b[1] = (bf16_t)hi;
  return x.u;
}
DEVI f32x4 mfma16(bf16x8 a, bf16x8 b, f32x4 c) {
  return __builtin_amdgcn_mfma_f32_16x16x32_bf16(a, b, c, 0, 0, 0);
}

// aux: CPol bits, SC0=1, NT=2, SC1=16.  17 = SC0|SC1 = device-coherent (MALL).
#define GLDS16_COH(g, s)                                                       \
  __builtin_amdgcn_global_load_lds(                                            \
      (const __attribute__((address_space(1))) void*)(const void*)(g),         \
      (__attribute__((address_space(3))) void*)(void*)(s), 16, 0, 17)
#define WAIT_LGKM0 asm volatile("s_waitcnt lgkmcnt(0)" ::: "memory")
#define WAIT_VM0   asm volatile("s_waitcnt vmcnt(0)" ::: "memory")
#define BARRIER_RAW                                                            \
  do { __builtin_amdgcn_s_barrier(); __builtin_amdgcn_sched_barrier(0); } while (0)

__global__ void k_init(int* flags) {
  int i = threadIdx.x;
  if (i < 256) flags[i] = 0;
}

// x fp32 [dir][b][t][i]  ->  bf16 t-major [dir][t][b][i]
__global__ void k_convx(const float* __restrict__ xf, const float* __restrict__ xb,
                        bf16_t* __restrict__ dst) {
  size_t og = (size_t)blockIdx.x * blockDim.x + threadIdx.x;
  int i8  = (int)(og & 127);
  int b   = (int)((og >> 7) & 63);
  int t   = (int)((og >> 13) & 511);
  int dir = (int)(og >> 22);
  const float* src = (dir ? xb : xf) + (((size_t)b * Ss + t) * Ii + (size_t)i8 * 8);
  f32x4 a = *(const f32x4*)src;
  f32x4 c = *(const f32x4*)(src + 4);
  *(bf16x8*)(dst + og * 8) = cvt8(a, c);
}

template <bool XBF>
__global__ void __launch_bounds__(512, 2)
k_lstm(const float* __restrict__ xf, const float* __restrict__ xb,
       const float* __restrict__ Wih_f, const float* __restrict__ Whh_f,
       const float* __restrict__ bih_f, const float* __restrict__ bhh_f,
       const float* __restrict__ Wih_b, const float* __restrict__ Whh_b,
       const float* __restrict__ bih_b, const float* __restrict__ bhh_b,
       float* __restrict__ out,
       const bf16_t* __restrict__ xbfin, bf16_t* __restrict__ hring,
       int* __restrict__ flags) {
  extern __shared__ char lds[];
  char* PA = lds;                 // h half-panel [64 r][512 k] bf16 = 64 KiB
  char* PB = lds + 65536;
  float* part = (float*)(lds + 131072);   // [4 kq][64 b][32 c] f32 = 32 KiB

  const int tid = threadIdx.x;
  const int bid = blockIdx.x;
  const int dir = bid & 1;
  const int db  = bid >> 1;
  const int n0  = db * 8;
  const int w   = tid >> 6, l = tid & 63;
  const int u   = l >> 4, l15 = l & 15;
  const int m   = w & 1;        // M swath (rows 32m..32m+31)
  const int kq  = w >> 1;       // K stripe (128-elem blocks of each half-panel)

  const float* Wih = dir ? Wih_b : Wih_f;
  const float* Whh = dir ? Whh_b : Whh_f;
  const float* bih = dir ? bih_b : bih_f;
  const float* bhh = dir ? bhh_b : bhh_f;
  const float* x32 = dir ? xb : xf;
  const bf16_t* xbase = xbfin + (size_t)dir * Ss * Bb * Ii;       // [t][b][i]
  bf16_t* hr = hring + (size_t)dir * 2 * Bb * Hh;                 // [par][b][h]
  float* outD = out + (size_t)dir * Bb * Ss * Hh;
  int* myflags = flags + dir * 128;

  // ---- one-time: W into VGPRs as B-fragments -------------------------------
  bf16x8 wr[2][2][4][2];
#pragma unroll
  for (int mat = 0; mat < 2; ++mat)
#pragma unroll
    for (int p = 0; p < 2; ++p)
#pragma unroll
      for (int ks = 0; ks < 4; ++ks)
#pragma unroll
        for (int nt = 0; nt < 2; ++nt) {
          int c = nt * 16 + l15;
          int j = (c >> 3) * 1024 + n0 + (c & 7);
          int k = p * 512 + kq * 128 + ks * 32 + u * 8;
          const float* sp = (mat ? Whh : Wih) + (size_t)j * 1024 + k;
          wr[mat][p][ks][nt] = cvt8(*(const f32x4*)sp, *(const f32x4*)(sp + 4));
        }

  // bias for the elementwise phase: thread -> (eb = tid>>3, en = tid&7)
  const int eb = tid >> 3, en = tid & 7;
  const int nj = n0 + en;
  float bi0 = bih[nj] + bhh[nj];
  float bi1 = bih[1024 + nj] + bhh[1024 + nj];
  float bi2 = bih[2048 + nj] + bhh[2048 + nj];
  float bi3 = bih[3072 + nj] + bhh[3072 + nj];

  // h A-fragment LDS offsets (r5 panel layout, granule swizzle slot^(row&7))
  int aoff0[4], aoff1[4];
#pragma unroll
  for (int ks = 0; ks < 4; ++ks) {
    int r0 = m * 32 + l15;
    int r1 = r0 + 16;
    int sl = kq * 16 + ks * 4 + u;
    aoff0[ks] = r0 * 1024 + ((sl ^ (r0 & 7)) << 4);
    aoff1[ks] = r1 * 1024 + ((sl ^ (r1 & 7)) << 4);
  }

  // h DMA (r5-proven): wave w writes rows w*8+i; source granule l^i.
  auto STAGE_H = [&](char* panel, const bf16_t* srcb) {
#pragma unroll
    for (int i = 0; i < 8; ++i) {
      const bf16_t* gp = srcb + (size_t)(w * 8 + i) * 1024 + ((l ^ i) << 3);
      GLDS16_COH(gp, panel + (w * 8 + i) * 1024);
    }
  };

  // ---- x A-fragments live in REGISTERS: xa[p*8 + ks*2 + r01] --------------
  bf16x8 xa[16];
  const int xr0 = m * 32 + l15;          // a0 row
  auto LOADX = [&](int tt) {
#pragma unroll
    for (int p = 0; p < 2; ++p)
#pragma unroll
      for (int ks = 0; ks < 4; ++ks)
#pragma unroll
        for (int r01 = 0; r01 < 2; ++r01) {
          int row = xr0 + r01 * 16;
          int k = p * 512 + kq * 128 + ks * 32 + u * 8;
          if constexpr (XBF) {
            xa[p * 8 + ks * 2 + r01] =
                *(const bf16x8*)(xbase + (size_t)tt * (Bb * Ii) +
                                 (size_t)row * 1024 + k);
          } else {
            const float* sp = x32 + ((size_t)row * Ss + tt) * Ii + k;
            xa[p * 8 + ks * 2 + r01] =
                cvt8(*(const f32x4*)sp, *(const f32x4*)(sp + 4));
          }
        }
  };

  f32x4 acc00, acc01, acc10, acc11;
  // x GEMMs straight from registers (no LDS, no barrier)
#define COMPX                                                                  \
  do {                                                                         \
    _Pragma("unroll") for (int p = 0; p < 2; ++p)                              \
    _Pragma("unroll") for (int ks = 0; ks < 4; ++ks) {                         \
      bf16x8 a0_ = xa[p * 8 + ks * 2 + 0];                                     \
      bf16x8 a1_ = xa[p * 8 + ks * 2 + 1];                                     \
      acc00 = mfma16(a0_, wr[0][p][ks][0], acc00);                             \
      acc01 = mfma16(a0_, wr[0][p][ks][1], acc01);                             \
      acc10 = mfma16(a1_, wr[0][p][ks][0], acc10);                             \
      acc11 = mfma16(a1_, wr[0][p][ks][1], acc11);                             \
    }                                                                          \
  } while (0)
#define COMPH(panel, pC)                                                       \
  do {                                                                         \
    _Pragma("unroll") for (int ks = 0; ks < 4; ++ks) {                         \
      bf16x8 a0_ = *(const bf16x8*)((panel) + aoff0[ks]);                      \
      bf16x8 a1_ = *(const bf16x8*)((panel) + aoff1[ks]);                      \
      acc00 = mfma16(a0_, wr[1][pC][ks][0], acc00);                            \
      acc01 = mfma16(a0_, wr[1][pC][ks][1], acc01);                            \
      acc10 = mfma16(a1_, wr[1][pC][ks][0], acc10);                            \
      acc11 = mfma16(a1_, wr[1][pC][ks][1], acc11);                            \
    }                                                                          \
  } while (0)

  float c_reg = 0.f;

  // prologue: x fragments for the first timestep
  LOADX(dir ? (Ss - 1) : 0);

  for (int step = 0; step < Ss; ++step) {
    const int t  = dir ? (Ss - 1 - step) : step;
    const int tn = dir ? (Ss - 2 - step) : (step + 1);
    const bf16_t* hbase = hr + (size_t)((step - 1) & 1) * (Bb * Hh);

    acc00 = f32x4{0.f, 0.f, 0.f, 0.f}; acc01 = acc00; acc10 = acc00; acc11 = acc00;

    // B2: x GEMMs from registers (compiler waits on the shadow loads)
    COMPX;

    // B3: poll producer flags (r5-proven spin), then barrier
    if (step > 0 && tid < 128) {
      const int* fp = &myflags[tid];
      while (__hip_atomic_load(fp, __ATOMIC_RELAXED, __HIP_MEMORY_SCOPE_AGENT) < step) {
      }
    }
    BARRIER_RAW;

    // B4: H phase (r5 verbatim): one DMA burst, one drain, one barrier
    if (step > 0) {
      STAGE_H(PA, hbase);
      STAGE_H(PB, hbase + 512);
      WAIT_VM0; BARRIER_RAW;
      COMPH(PA, 0);
      COMPH(PB, 1);
      WAIT_LGKM0;
    }

    // B5: write K-partials to LDS, XOR-swizzled column: Cs = C ^ ((R&7)<<2)
#pragma unroll
    for (int rr = 0; rr < 2; ++rr)
#pragma unroll
      for (int nt = 0; nt < 2; ++nt) {
        f32x4 a = (rr == 0) ? (nt == 0 ? acc00 : acc01) : (nt == 0 ? acc10 : acc11);
#pragma unroll
        for (int q = 0; q < 4; ++q) {
          int R = m * 32 + rr * 16 + u * 4 + q;
          int C = nt * 16 + l15;
          part[(kq * 64 + R) * 32 + (C ^ ((R & 7) << 2))] = a[q];
        }
      }
    WAIT_LGKM0; BARRIER_RAW;

    // B6: elementwise gates; thread -> (eb, en); read swizzle key (eb&7)<<2
    float hval;
    {
      const int sk = (eb & 7) << 2;
      float g0 = bi0, g1 = bi1, g2 = bi2, g3 = bi3;
#pragma unroll
      for (int q = 0; q < 4; ++q) {
        const float* pp = &part[(q * 64 + eb) * 32];
        g0 += pp[en ^ sk]; g1 += pp[(8 + en) ^ sk];
        g2 += pp[(16 + en) ^ sk]; g3 += pp[(24 + en) ^ sk];
      }
      float ig = fast_sig(g0), fg = fast_sig(g1);
      float gg = fast_tanh(g2), og = fast_sig(g3);
      c_reg = fg * c_reg + ig * gg;
      hval = og * fast_tanh(c_reg);
      // pack 4 lanes' h into one 8B agent store (write-through to MALL)
      uint32_t p01 = pk_bf16(hval, __shfl_xor(hval, 1));
      uint32_t p23 = __shfl_xor(p01, 2);
      if ((en & 3) == 0) {
        uint64_t q8 = (uint64_t)p01 | ((uint64_t)p23 << 32);
        uint64_t* dst = (uint64_t*)&hr[(size_t)(step & 1) * (Bb * Hh) +
                                       (size_t)eb * Hh + n0 + (en & 4)];
        __hip_atomic_store(dst, q8, __ATOMIC_RELAXED, __HIP_MEMORY_SCOPE_AGENT);
      }
    }

    // B7: drain this step's h-stores, then release this block's flag.
    WAIT_VM0; BARRIER_RAW;
    if (tid == 0) {
      __hip_atomic_store(&myflags[db], step + 1, __ATOMIC_RELAXED,
                         __HIP_MEMORY_SCOPE_AGENT);
    }

    // B8 (shadow, off the release chain): out-store + next x frags into regs
    outD[(size_t)eb * (Ss * Hh) + (size_t)t * Hh + n0 + en] = hval;
    if (step < Ss - 1) LOADX(tn);
  }
#undef COMPX
#undef COMPH
}

extern "C" void kernel_launch(void* const* d_in, const int* in_sizes, int n_in,
                              void* d_out, int out_size, void* d_ws, size_t ws_size,
                              hipStream_t stream) {
  (void)in_sizes; (void)n_in; (void)out_size;
  const float* xf    = (const float*)d_in[0];
  const float* xb    = (const float*)d_in[1];
  const float* Wih_f = (const float*)d_in[2];
  const float* Whh_f = (const float*)d_in[3];
  const float* bih_f = (const float*)d_in[4];
  const float* bhh_f = (const float*)d_in[5];
  const float* Wih_b = (const float*)d_in[6];
  const float* Whh_b = (const float*)d_in[7];
  const float* bih_b = (const float*)d_in[8];
  const float* bhh_b = (const float*)d_in[9];
  float* outp = (float*)d_out;
  char* ws = (char*)d_ws;
  int* flagsp = (int*)(ws + WS_FLAGS);
  bf16_t* hringp = (bf16_t*)(ws + WS_HRING);
  const bf16_t* xbfp = (const bf16_t*)(ws + WS_XBF);
  const bool use_xbf = ws_size >= WS_NEED_XBF;

  hipLaunchKernelGGL(k_init, dim3(1), dim3(256), 0, stream, flagsp);
  if (use_xbf) {
    hipLaunchKernelGGL(k_convx, dim3(32768), dim3(256), 0, stream,
                       xf, xb, (bf16_t*)(ws + WS_XBF));
  }

  void* args[] = {&xf, &xb, &Wih_f, &Whh_f, &bih_f, &bhh_f,
                  &Wih_b, &Whh_b, &bih_b, &bhh_b,
                  &outp, &xbfp, &hringp, &flagsp};
  using KFn = void (*)(const float*, const float*, const float*, const float*,
                       const float*, const float*, const float*, const float*,
                       const float*, const float*, float*, const bf16_t*,
                       bf16_t*, int*);
  KFn kp = use_xbf ? (KFn)k_lstm<true> : (KFn)k_lstm<false>;
  hipFuncSetAttribute((const void*)kp, hipFuncAttributeMaxDynamicSharedMemorySize,
                      LDS_TOTAL);
  hipLaunchCooperativeKernel((const void*)kp, dim3(256), dim3(512), args,
                             LDS_TOTAL, stream);
}

// Round 16
// 3266.095 us; speedup vs baseline: 1.7978x; 1.7978x over previous
//
#include <hip/hip_runtime.h>
#include <hip/hip_bf16.h>
#include <cstdint>

// ---------------------------------------------------------------------------
// BiLSTM layer, persistent kernel (round 16 = r15 + prologue release fix).
//   B=64, S=512, I=H=1024.  out = [fwd(B,S,H) | bwd(B,S,H)] fp32.
// 256 blocks x 512 threads (8 waves), 1 block/CU. dir=bid&1, db=bid>>1.
// Weights (W_ih|W_hh, K=2048) VGPR-resident as MFMA B-fragments.
// h exchange: agent write-through stores -> MALL; SC0|SC1 bypass DMA loads.
//
// Rolling bf16-x window (r15): 8-slot, 2 MiB window in ws. Blocks db<64
// convert one batch-row of x_{s+LA} per step (8B load at step top, packed
// u32 agent-store folded into the B7 drain). Existing flag protocol gives
// the ordering proof; slot distance LA=4 mod 8 excludes overwrite races.
// Staging = 128KB bypass DMA (r5's proven h semantics) instead of 256KB
// fp32 reg-cvt -> halves the per-XCD x service bytes.
//
// ROUND-16 FIX (r15 failed validation on one output): the prologue
// published flag 0 after WAIT_VM0 but WITHOUT a barrier. vmcnt drains are
// per-thread; threads 1..511's conversion stores could still be in flight
// when tid 0's flag landed -> consumers read a partial x window; the
// corruption propagates through the whole recurrence. Fix = drain ->
// BARRIER -> publish (same discipline as the main loop's B7).
// ---------------------------------------------------------------------------

typedef __bf16 bf16_t;
typedef bf16_t bf16x8 __attribute__((ext_vector_type(8)));
typedef float  f32x4  __attribute__((ext_vector_type(4)));

#define DEVI __device__ __forceinline__

constexpr int Bb = 64, Ss = 512, Ii = 1024, Hh = 1024;
constexpr int W = 8, LA = 4;               // window slots, lookahead
constexpr size_t WS_FLAGS = 0;             // 256 ints (2 dirs x 128 blocks)
constexpr size_t WS_HRING = 4096;          // 2*2*64*1024 bf16 = 524288 B
constexpr size_t WS_XWIN  = 528384;        // [dir][slot][b][i] bf16
constexpr size_t XWIN_BYTES = 2ull * W * Bb * Ii * 2;   // 2 MiB
constexpr size_t WS_NEED_XW = WS_XWIN + XWIN_BYTES;     // ~2.6 MiB
constexpr int LDS_TOTAL = 163840;          // PA 64K | PB 64K | part 32K

DEVI float fast_sig(float x) {
  float z = __expf(-fabsf(x));
  float r = __builtin_amdgcn_rcpf(1.f + z);
  return x >= 0.f ? r : z * r;
}
DEVI float fast_tanh(float x) {
  float z = __expf(-2.f * fabsf(x));
  float r = (1.f - z) * __builtin_amdgcn_rcpf(1.f + z);
  return x >= 0.f ? r : -r;
}
DEVI bf16x8 cvt8(f32x4 a, f32x4 b) {
  bf16x8 r;
  r[0] = (bf16_t)a[0]; r[1] = (bf16_t)a[1]; r[2] = (bf16_t)a[2]; r[3] = (bf16_t)a[3];
  r[4] = (bf16_t)b[0]; r[5] = (bf16_t)b[1]; r[6] = (bf16_t)b[2]; r[7] = (bf16_t)b[3];
  return r;
}
DEVI uint32_t pk_bf16(float lo, float hi) {
  union { bf16_t b[2]; uint32_t u; } x;
  x.b[0] = (bf16_t)lo; x.b[1] = (bf16_t)hi;
  return x.u;
}
DEVI f32x4 mfma16(bf16x8 a, bf16x8 b, f32x4 c) {
  return __builtin_amdgcn_mfma_f32_16x16x32_bf16(a, b, c, 0, 0, 0);
}

// aux: CPol bits, SC0=1, NT=2, SC1=16.  17 = SC0|SC1 = device-coherent (MALL).
#define GLDS16_COH(g, s)                                                       \
  __builtin_amdgcn_global_load_lds(                                            \
      (const __attribute__((address_space(1))) void*)(const void*)(g),         \
      (__attribute__((address_space(3))) void*)(void*)(s), 16, 0, 17)
#define WAIT_LGKM0 asm volatile("s_waitcnt lgkmcnt(0)" ::: "memory")
#define WAIT_VM0   asm volatile("s_waitcnt vmcnt(0)" ::: "memory")
#define BARRIER_RAW                                                            \
  do { __builtin_amdgcn_s_barrier(); __builtin_amdgcn_sched_barrier(0); } while (0)

__global__ void k_init(int* flags) {
  int i = threadIdx.x;
  if (i < 256) flags[i] = -1;        // -1: prologue not yet done
}

template <bool XW>
__global__ void __launch_bounds__(512, 2)
k_lstm(const float* __restrict__ xf, const float* __restrict__ xb,
       const float* __restrict__ Wih_f, const float* __restrict__ Whh_f,
       const float* __restrict__ bih_f, const float* __restrict__ bhh_f,
       const float* __restrict__ Wih_b, const float* __restrict__ Whh_b,
       const float* __restrict__ bih_b, const float* __restrict__ bhh_b,
       float* __restrict__ out,
       bf16_t* __restrict__ xw, bf16_t* __restrict__ hring,
       int* __restrict__ flags) {
  extern __shared__ char lds[];
  char* PA = lds;                 // half-panel [64 rows][512 k] bf16 = 64 KiB
  char* PB = lds + 65536;
  float* part = (float*)(lds + 131072);   // [4 kq][64 b][32 c] f32 = 32 KiB

  const int tid = threadIdx.x;
  const int bid = blockIdx.x;
  const int dir = bid & 1;
  const int db  = bid >> 1;
  const int n0  = db * 8;
  const int w   = tid >> 6, l = tid & 63;
  const int u   = l >> 4, l15 = l & 15;
  const int m   = w & 1;        // M swath (rows 32m..32m+31)
  const int kq  = w >> 1;       // K stripe (128-elem blocks of each half-panel)

  const float* Wih = dir ? Wih_b : Wih_f;
  const float* Whh = dir ? Whh_b : Whh_f;
  const float* bih = dir ? bih_b : bih_f;
  const float* bhh = dir ? bhh_b : bhh_f;
  const float* x32 = dir ? xb : xf;
  bf16_t* hr = hring + (size_t)dir * 2 * Bb * Hh;                 // [par][b][h]
  bf16_t* xwd = xw + (size_t)dir * W * Bb * Ii;                   // [slot][b][i]
  float* outD = out + (size_t)dir * Bb * Ss * Hh;
  int* myflags = flags + dir * 128;

  // ---- one-time: W into VGPRs as B-fragments -------------------------------
  bf16x8 wr[2][2][4][2];
#pragma unroll
  for (int mat = 0; mat < 2; ++mat)
#pragma unroll
    for (int p = 0; p < 2; ++p)
#pragma unroll
      for (int ks = 0; ks < 4; ++ks)
#pragma unroll
        for (int nt = 0; nt < 2; ++nt) {
          int c = nt * 16 + l15;
          int j = (c >> 3) * 1024 + n0 + (c & 7);
          int k = p * 512 + kq * 128 + ks * 32 + u * 8;
          const float* sp = (mat ? Whh : Wih) + (size_t)j * 1024 + k;
          wr[mat][p][ks][nt] = cvt8(*(const f32x4*)sp, *(const f32x4*)(sp + 4));
        }

  // bias for the elementwise phase: thread -> (eb = tid>>3, en = tid&7)
  const int eb = tid >> 3, en = tid & 7;
  const int nj = n0 + en;
  float bi0 = bih[nj] + bhh[nj];
  float bi1 = bih[1024 + nj] + bhh[1024 + nj];
  float bi2 = bih[2048 + nj] + bhh[2048 + nj];
  float bi3 = bih[3072 + nj] + bhh[3072 + nj];

  // A-fragment LDS offsets (panel [64][512]bf16, granule swizzle slot^(row&7))
  int aoff0[4], aoff1[4];
#pragma unroll
  for (int ks = 0; ks < 4; ++ks) {
    int r0 = m * 32 + l15;
    int r1 = r0 + 16;
    int sl = kq * 16 + ks * 4 + u;
    aoff0[ks] = r0 * 1024 + ((sl ^ (r0 & 7)) << 4);
    aoff1[ks] = r1 * 1024 + ((sl ^ (r1 & 7)) << 4);
  }

  // bypass DMA staging (r5-proven l^i swizzle): used for h ring AND x window
  auto STAGE_P = [&](char* panel, const bf16_t* srcb) {
#pragma unroll
    for (int i = 0; i < 8; ++i) {
      const bf16_t* gp = srcb + (size_t)(w * 8 + i) * 1024 + ((l ^ i) << 3);
      GLDS16_COH(gp, panel + (w * 8 + i) * 1024);
    }
  };
  // fallback: fp32 x staged through regs + cvt (r5 verbatim)
  auto STAGE_XF = [&](char* panel, const float* srcb) {
#pragma unroll
    for (int i = 0; i < 8; ++i) {
      int r = w * 8 + i;
      const float* sp = srcb + (size_t)r * (Ss * Ii) + ((l ^ i) << 3);
      f32x4 a = *(const f32x4*)sp;
      f32x4 b = *(const f32x4*)(sp + 4);
      *(bf16x8*)(panel + r * 1024 + l * 16) = cvt8(a, b);
    }
  };

  f32x4 acc00, acc01, acc10, acc11;
#define COMPUTE(panel, matC, pC)                                               \
  do {                                                                         \
    _Pragma("unroll") for (int ks = 0; ks < 4; ++ks) {                         \
      bf16x8 a0_ = *(const bf16x8*)((panel) + aoff0[ks]);                      \
      bf16x8 a1_ = *(const bf16x8*)((panel) + aoff1[ks]);                      \
      acc00 = mfma16(a0_, wr[matC][pC][ks][0], acc00);                         \
      acc01 = mfma16(a0_, wr[matC][pC][ks][1], acc01);                         \
      acc10 = mfma16(a1_, wr[matC][pC][ks][0], acc10);                         \
      acc11 = mfma16(a1_, wr[matC][pC][ks][1], acc11);                         \
    }                                                                          \
  } while (0)

  float c_reg = 0.f;
  const bool conv = XW && (db < 64);      // this block converts x batch-row db

  // ---- prologue -----------------------------------------------------------
  if constexpr (XW) {
    if (conv) {
#pragma unroll
      for (int s0 = 0; s0 < LA; ++s0) {
        int tc = dir ? (Ss - 1 - s0) : s0;
        float2 cv = *(const float2*)(x32 + ((size_t)db * Ss + tc) * Ii + tid * 2);
        uint32_t* dst = (uint32_t*)(xwd + (size_t)s0 * (Bb * Ii) + db * 1024 + tid * 2);
        __hip_atomic_store(dst, pk_bf16(cv.x, cv.y), __ATOMIC_RELAXED,
                           __HIP_MEMORY_SCOPE_AGENT);
      }
    }
    WAIT_VM0;          // per-thread drain of own conversion stores
  }
  // FIX: barrier BEFORE the publish — all 512 threads' stores must be at the
  // MALL before tid 0 releases flag 0 (r15 raced here; B7 discipline applied).
  BARRIER_RAW;
  if (tid == 0) {
    __hip_atomic_store(&myflags[db], 0, __ATOMIC_RELAXED, __HIP_MEMORY_SCOPE_AGENT);
  }
  if (tid < 128) {   // wait chip-wide prologue completion
    const int* fp = &myflags[tid];
    while (__hip_atomic_load(fp, __ATOMIC_RELAXED, __HIP_MEMORY_SCOPE_AGENT) < 0) {
    }
  }
  BARRIER_RAW;
  // stage s=0 panels
  if constexpr (XW) {
    STAGE_P(PA, xwd);
    STAGE_P(PB, xwd + 512);
  } else {
    int t0 = dir ? (Ss - 1) : 0;
    STAGE_XF(PA, x32 + (size_t)t0 * Ii);
    STAGE_XF(PB, x32 + (size_t)t0 * Ii + 512);
  }

  for (int step = 0; step < Ss; ++step) {
    const int t  = dir ? (Ss - 1 - step) : step;
    const int tn = dir ? (Ss - 2 - step) : (step + 1);
    const bf16_t* hbase = hr + (size_t)((step - 1) & 1) * (Bb * Hh);

    // B1: x panels (prefetched at prev tail / prologue) resident
    WAIT_VM0; WAIT_LGKM0; BARRIER_RAW;

    // issue this step's conversion LOAD early (flies under the whole step)
    float2 cx;
    const bool cnow = conv && (step + LA) < Ss;
    if (cnow) {
      int tc = dir ? (Ss - 1 - (step + LA)) : (step + LA);
      cx = *(const float2*)(x32 + ((size_t)db * Ss + tc) * Ii + tid * 2);
    }

    acc00 = f32x4{0.f, 0.f, 0.f, 0.f}; acc01 = acc00; acc10 = acc00; acc11 = acc00;

    // B2: both x half-panel GEMMs — block-local work, runs in the poll shadow
    COMPUTE(PA, 0, 0);
    COMPUTE(PB, 0, 1);
    WAIT_LGKM0;                      // PA/PB reusable

    // B3: poll producer flags (one per producer block), then barrier
    if (step > 0 && tid < 128) {
      const int* fp = &myflags[tid];
      while (__hip_atomic_load(fp, __ATOMIC_RELAXED, __HIP_MEMORY_SCOPE_AGENT) < step) {
      }
    }
    BARRIER_RAW;

    // B4: single H phase: issue H0+H1, one drain, one barrier, both hh GEMMs
    if (step > 0) {
      STAGE_P(PA, hbase);
      STAGE_P(PB, hbase + 512);
      WAIT_VM0; BARRIER_RAW;
      COMPUTE(PA, 1, 0);
      COMPUTE(PB, 1, 1);
      WAIT_LGKM0;                    // PA/PB reusable for next prefetch
    }

    // B5: write K-partials to LDS, XOR-swizzled column: Cs = C ^ ((R&7)<<2)
#pragma unroll
    for (int rr = 0; rr < 2; ++rr)
#pragma unroll
      for (int nt = 0; nt < 2; ++nt) {
        f32x4 a = (rr == 0) ? (nt == 0 ? acc00 : acc01) : (nt == 0 ? acc10 : acc11);
#pragma unroll
        for (int q = 0; q < 4; ++q) {
          int R = m * 32 + rr * 16 + u * 4 + q;
          int C = nt * 16 + l15;
          part[(kq * 64 + R) * 32 + (C ^ ((R & 7) << 2))] = a[q];
        }
      }
    WAIT_LGKM0; BARRIER_RAW;

    // B6: elementwise gates; thread -> (eb, en); read swizzle key (eb&7)<<2
    float hval;
    {
      const int sk = (eb & 7) << 2;
      float g0 = bi0, g1 = bi1, g2 = bi2, g3 = bi3;
#pragma unroll
      for (int q = 0; q < 4; ++q) {
        const float* pp = &part[(q * 64 + eb) * 32];
        g0 += pp[en ^ sk]; g1 += pp[(8 + en) ^ sk];
        g2 += pp[(16 + en) ^ sk]; g3 += pp[(24 + en) ^ sk];
      }
      float ig = fast_sig(g0), fg = fast_sig(g1);
      float gg = fast_tanh(g2), og = fast_sig(g3);
      c_reg = fg * c_reg + ig * gg;
      hval = og * fast_tanh(c_reg);
      // pack 4 lanes' h into one 8B agent store (write-through to MALL)
      uint32_t p01 = pk_bf16(hval, __shfl_xor(hval, 1));
      uint32_t p23 = __shfl_xor(p01, 2);
      if ((en & 3) == 0) {
        uint64_t q8 = (uint64_t)p01 | ((uint64_t)p23 << 32);
        uint64_t* dst = (uint64_t*)&hr[(size_t)(step & 1) * (Bb * Hh) +
                                       (size_t)eb * Hh + n0 + (en & 4)];
        __hip_atomic_store(dst, q8, __ATOMIC_RELAXED, __HIP_MEMORY_SCOPE_AGENT);
      }
    }
    // conversion store for step+LA (drained together with the h stores below)
    if (cnow) {
      uint32_t* dst = (uint32_t*)(xwd + (size_t)((step + LA) & (W - 1)) * (Bb * Ii) +
                                  db * 1024 + tid * 2);
      __hip_atomic_store(dst, pk_bf16(cx.x, cx.y), __ATOMIC_RELAXED,
                         __HIP_MEMORY_SCOPE_AGENT);
    }

    // B7: drain this step's stores (h + conversion), barrier, release flag.
    WAIT_VM0; BARRIER_RAW;
    if (tid == 0) {
      __hip_atomic_store(&myflags[db], step + 1, __ATOMIC_RELAXED,
                         __HIP_MEMORY_SCOPE_AGENT);
    }

    // B8: consumer-invisible tail: out-store + next-step x staging.
    outD[(size_t)eb * (Ss * Hh) + (size_t)t * Hh + n0 + en] = hval;
    if (step < Ss - 1) {
      if constexpr (XW) {
        const bf16_t* wsl = xwd + (size_t)((step + 1) & (W - 1)) * (Bb * Ii);
        STAGE_P(PA, wsl);
        STAGE_P(PB, wsl + 512);
      } else {
        STAGE_XF(PA, x32 + (size_t)tn * Ii);
        STAGE_XF(PB, x32 + (size_t)tn * Ii + 512);
      }
    }
  }
#undef COMPUTE
}

extern "C" void kernel_launch(void* const* d_in, const int* in_sizes, int n_in,
                              void* d_out, int out_size, void* d_ws, size_t ws_size,
                              hipStream_t stream) {
  (void)in_sizes; (void)n_in; (void)out_size;
  const float* xf    = (const float*)d_in[0];
  const float* xb    = (const float*)d_in[1];
  const float* Wih_f = (const float*)d_in[2];
  const float* Whh_f = (const float*)d_in[3];
  const float* bih_f = (const float*)d_in[4];
  const float* bhh_f = (const float*)d_in[5];
  const float* Wih_b = (const float*)d_in[6];
  const float* Whh_b = (const float*)d_in[7];
  const float* bih_b = (const float*)d_in[8];
  const float* bhh_b = (const float*)d_in[9];
  float* outp = (float*)d_out;
  char* ws = (char*)d_ws;
  int* flagsp = (int*)(ws + WS_FLAGS);
  bf16_t* hringp = (bf16_t*)(ws + WS_HRING);
  bf16_t* xwp = (bf16_t*)(ws + WS_XWIN);
  const bool use_xw = ws_size >= WS_NEED_XW;

  hipLaunchKernelGGL(k_init, dim3(1), dim3(256), 0, stream, flagsp);

  void* args[] = {&xf, &xb, &Wih_f, &Whh_f, &bih_f, &bhh_f,
                  &Wih_b, &Whh_b, &bih_b, &bhh_b,
                  &outp, &xwp, &hringp, &flagsp};
  using KFn = void (*)(const float*, const float*, const float*, const float*,
                       const float*, const float*, const float*, const float*,
                       const float*, const float*, float*, bf16_t*,
                       bf16_t*, int*);
  KFn kp = use_xw ? (KFn)k_lstm<true> : (KFn)k_lstm<false>;
  hipFuncSetAttribute((const void*)kp, hipFuncAttributeMaxDynamicSharedMemorySize,
                      LDS_TOTAL);
  hipLaunchCooperativeKernel((const void*)kp, dim3(256), dim3(512), args,
                             LDS_TOTAL, stream);
}